// Round 3
// baseline (288.238 us; speedup 1.0000x reference)
//
#include <hip/hip_runtime.h>
#include <math.h>

// ---------------------------------------------------------------------------
// MinGRU, 2 layers. B=8, S=4096, D=H=512.
// Round 7: round-6 pipeline with the LDS-DMA offset bug fixed. The
// global_load_lds offset immediate applies to BOTH global and LDS addresses
// (LDS dest = M0 + inst_offset + lane*size), so round 6's K-step-via-offset
// wrote LDS at shifted addresses -> uninitialized reads -> NaN. Fix: runtime-K
// loop + pointer increments + offset=0 (runtime addresses also prevent the
// backend from folding constants into the dual-use offset field).
// Pipeline: STAGE(next buf) -> COMPUTE(cur buf) -> one barrier per K-step
// (BK=32, 16 steps), double-buffered 2x16KB LDS aliased by the epilogue tile.
// Scan: Lc=32/Nc=128, csum-free fused pass1, h0b aliases xb. 7 dispatches.
// ---------------------------------------------------------------------------

typedef unsigned short u16;
typedef __attribute__((ext_vector_type(8))) short short8;   // 8 bf16 = 4 VGPR
typedef __attribute__((ext_vector_type(4))) float f32x4;

__device__ __forceinline__ u16 f2bf(float f) {
    unsigned int u = __float_as_uint(f);
    return (u16)((u + 0x7fffu + ((u >> 16) & 1u)) >> 16);   // RNE
}
__device__ __forceinline__ float bf2f(u16 u) {
    return __uint_as_float(((unsigned int)u) << 16);
}
__device__ __forceinline__ void async16(const void* g, void* l) {
    __builtin_amdgcn_global_load_lds(
        (const __attribute__((address_space(1))) unsigned int*)g,
        (__attribute__((address_space(3))) unsigned int*)l, 16, 0, 0);
}
__device__ __forceinline__ float fastrcp(float x) { return __builtin_amdgcn_rcpf(x); }

// c = sigmoid(-gate); v = sigmoid(gate) * g(hid). 2 exp + 2 v_rcp.
__device__ __forceinline__ void coeff_val(float gate, float hid, float& c, float& v)
{
    float cc = fastrcp(1.0f + __expf(gate));      // sigmoid(-gate)
    float gp = hid + 0.5f;                        // hid >= 0 branch
    float gn = fastrcp(1.0f + __expf(-hid));      // sigmoid(hid), hid < 0 branch
    float g  = (hid >= 0.0f) ? gp : gn;
    c = cc;
    v = (1.0f - cc) * g;
}

// ---------------------------------------------------------------------------
// Fused cast: x (nx4 float4s) then w0, w1 (nw4 float4s each), one flat grid.
// ---------------------------------------------------------------------------
__global__ __launch_bounds__(256) void cast3(
    const float* __restrict__ x,  u16* __restrict__ xb,  int nx4,
    const float* __restrict__ w0, u16* __restrict__ w0b,
    const float* __restrict__ w1, u16* __restrict__ w1b, int nw4)
{
    int i = blockIdx.x * 256 + threadIdx.x;
    const float* src; u16* dst; int idx;
    if (i < nx4)                { src = x;  dst = xb;  idx = i; }
    else if (i < nx4 + nw4)     { src = w0; dst = w0b; idx = i - nx4; }
    else if (i < nx4 + 2 * nw4) { src = w1; dst = w1b; idx = i - nx4 - nw4; }
    else return;
    float4 v = ((const float4*)src)[idx];
    ushort4 o = make_ushort4(f2bf(v.x), f2bf(v.y), f2bf(v.z), f2bf(v.w));
    ((ushort4*)dst)[idx] = o;
}

// ---------------------------------------------------------------------------
// gemm_fused: C = A(128 rows) . Wperm^T; register-direct epilogue computes
// (c,v), packs bf16 pairs into an LDS tile for the coalesced gh store and the
// fused pass1 (4 chunks of 32 rows). Grid (8, M/128), XCD-swizzled.
// W tile row r: ch(r) = (r&31) + ((r&64)>>1), is_hid = (r>>5)&1,
//               W row = bn*64 + ch + is_hid*512.
// => wave half w1: frags j=0,1 gate of ch w1*32+j*16+fm; j=2,3 hidden (same).
// ---------------------------------------------------------------------------
#define TST 136   // epilogue (c,v)-tile row stride in u16 (68 dwords)

__global__ __launch_bounds__(256) void gemm_fused(
    const u16* __restrict__ A, const u16* __restrict__ W,
    const float* __restrict__ bias, u16* __restrict__ gh,
    float* __restrict__ cA, float* __restrict__ cV, int K)
{
    __shared__ __align__(16) u16 lds[128 * TST];   // 34816 B; K-loop uses first 32 KB

    const int tid  = threadIdx.x;
    // XCD-aware swizzle: nwg = 2048 = 8 * 256 (divisible by 8 -> bijective).
    const int d    = blockIdx.y * 8 + blockIdx.x;
    const int cpx  = (int)(gridDim.x * gridDim.y) >> 3;
    const int t0   = (d & 7) * cpx + (d >> 3);
    const int bn   = t0 & 7;                // channel block [bn*64, bn*64+64)
    const int bm   = t0 >> 3;               // row block
    const int lane = tid & 63;
    const int wave = tid >> 6;
    const int wm   = (wave >> 1) * 64;
    const int wn   = (wave & 1) * 64;
    const int w1   = wave & 1;
    const int fm   = lane & 15;
    const int kb   = lane >> 4;

    // staging: 2 granules (16 B)/thread/operand; row = 64 B = 4 granules.
    // Pre-swizzled global source, linear LDS dest (global_load_lds rule).
    const int r0 = tid >> 2, q0 = (tid & 3) ^ (r0 & 3);
    const int r1 = r0 + 64,  q1 = (tid & 3) ^ (r1 & 3);
    const u16* Ap0 = A + (size_t)(bm * 128 + r0) * 512 + q0 * 8;
    const u16* Ap1 = A + (size_t)(bm * 128 + r1) * 512 + q1 * 8;
    const int wr0 = bn * 64 + (r0 & 31) + ((r0 & 32) ? 512 : 0);
    const int wr1 = bn * 64 + (r1 & 31) + 32 + ((r1 & 32) ? 512 : 0);
    const u16* Wp0 = W + (size_t)wr0 * 512 + q0 * 8;
    const u16* Wp1 = W + (size_t)wr1 * 512 + q1 * 8;

    // fragment read offsets (bytes) within a buffer; row stride 64 B.
    int offA[4], offB[4];
    #pragma unroll
    for (int i = 0; i < 4; ++i) {
        const int rowA = wm + i * 16 + fm;
        offA[i] = rowA * 64 + ((kb ^ (rowA & 3)) * 16);
        const int rowB = wn + i * 16 + fm;
        offB[i] = rowB * 64 + ((kb ^ (rowB & 3)) * 16);
    }

    f32x4 acc[4][4];
    #pragma unroll
    for (int i = 0; i < 4; ++i)
        #pragma unroll
        for (int j = 0; j < 4; ++j)
            acc[i][j] = (f32x4){0.f, 0.f, 0.f, 0.f};

    const char* AsB = (const char*)lds;

#define STAGE(NB) do { \
    char* dst_ = (char*)lds + (NB); \
    async16(Ap0, dst_ + tid * 16); \
    async16(Ap1, dst_ + (tid + 256) * 16); \
    async16(Wp0, dst_ + 8192 + tid * 16); \
    async16(Wp1, dst_ + 8192 + (tid + 256) * 16); \
    Ap0 += 32; Ap1 += 32; Wp0 += 32; Wp1 += 32; } while (0)

#define COMPUTE(CB) do { \
    const char* src_ = AsB + (CB); \
    short8 av[4], bw[4]; \
    _Pragma("unroll") for (int i = 0; i < 4; ++i) \
        av[i] = *(const short8*)(src_ + offA[i]); \
    _Pragma("unroll") for (int j = 0; j < 4; ++j) \
        bw[j] = *(const short8*)(src_ + 8192 + offB[j]); \
    _Pragma("unroll") for (int i = 0; i < 4; ++i) \
        _Pragma("unroll") for (int j = 0; j < 4; ++j) \
            acc[i][j] = __builtin_amdgcn_mfma_f32_16x16x32_bf16( \
                av[i], bw[j], acc[i][j], 0, 0, 0); \
} while (0)

    // Pipeline: stage(k+1) issued before compute(k); one barrier per step.
    // Runtime trip count (K is a kernel arg) keeps addresses in registers.
    int cb = 0;
    STAGE(0);
    __syncthreads();
    for (int kt = 32; kt < K; kt += 32) {
        STAGE(cb ^ 16384);
        COMPUTE(cb);
        __syncthreads();
        cb ^= 16384;
    }
    COMPUTE(cb);
    __syncthreads();   // before epilogue overwrites the K-loop buffers

#undef STAGE
#undef COMPUTE

    // ---- epilogue: coeff_val on f32 accumulators, pack (c,v) bf16 into LDS ----
    float bg[2], bh[2];
    #pragma unroll
    for (int jj = 0; jj < 2; ++jj) {
        const int chl = w1 * 32 + jj * 16 + fm;
        bg[jj] = bias[bn * 64 + chl];
        bh[jj] = bias[512 + bn * 64 + chl];
    }
    unsigned int* ldsw = (unsigned int*)lds;   // 68 dwords per row (TST/2)
    #pragma unroll
    for (int i = 0; i < 4; ++i)
        #pragma unroll
        for (int jj = 0; jj < 2; ++jj) {
            const int chl = w1 * 32 + jj * 16 + fm;
            const f32x4 g4 = acc[i][jj];        // gate fragment
            const f32x4 h4 = acc[i][jj + 2];    // hidden fragment, same channels
            #pragma unroll
            for (int r = 0; r < 4; ++r) {
                const int row = wm + i * 16 + kb * 4 + r;
                float c, v;
                coeff_val(g4[r] + bg[jj], h4[r] + bh[jj], c, v);
                ldsw[row * 68 + chl] = (unsigned int)f2bf(c)
                                     | ((unsigned int)f2bf(v) << 16);
            }
        }
    __syncthreads();

    // ---- coalesced gh store: 128 u16 of interleaved (c,v) per row ----
    #pragma unroll
    for (int it = 0; it < 8; ++it) {
        const int row = it * 16 + (tid >> 4);
        const int sc  = (tid & 15) * 8;
        short8 vv = *(const short8*)&lds[row * TST + sc];
        *(short8*)&gh[(size_t)(bm * 128 + row) * 1024 + bn * 128 + sc] = vv;
    }

    // ---- fused pass1: 4 chunks of 32 rows, serial per channel (rounded c,v
    //      so carry/replay stay consistent with pass3) ----
    const int ch = tid & 63;
    const int ck = tid >> 6;              // 0..3
    float Aa = 1.f, Vv = 0.f;
    #pragma unroll 4
    for (int s = 0; s < 32; ++s) {
        const unsigned int p = ldsw[(ck * 32 + s) * 68 + ch];
        const float c = bf2f((u16)p);
        const float v = bf2f((u16)(p >> 16));
        Aa *= c;
        Vv = fmaf(c, Vv, v);
    }
    const int bb  = bm >> 5;                 // 32 row-blocks per batch
    const int ckg = (bm & 31) * 4 + ck;      // global chunk in [0,128)
    const size_t idx = ((size_t)(bb * 128 + ckg)) * 512 + bn * 64 + ch;
    cA[idx] = Aa;
    cV[idx] = Vv;
}

// ---------------------------------------------------------------------------
// pass2: sequential combine across Nc chunks per batch. 2 channels/thread.
// ---------------------------------------------------------------------------
__global__ __launch_bounds__(256) void scan_pass2(
    const float* __restrict__ cA, const float* __restrict__ cV,
    float* __restrict__ carry, int Nc)
{
    const int tid = threadIdx.x;
    const int b = blockIdx.x;
    float s0 = 0.5f, s1 = 0.5f;   // h0
    #pragma unroll 8
    for (int ck = 0; ck < Nc; ++ck) {
        const size_t idx = (size_t)(b * Nc + ck) * 512 + 2 * tid;
        *(float2*)(carry + idx) = make_float2(s0, s1);
        float2 a = *(const float2*)(cA + idx);
        float2 v = *(const float2*)(cV + idx);
        s0 = fmaf(a.x, s0, v.x);
        s1 = fmaf(a.y, s1, v.y);
    }
}

// ---------------------------------------------------------------------------
// pass3: replay each chunk from its carry. gh holds interleaved (c,v) bf16
// pairs -> one ushort4 (8 B) load per step, no transcendentals.
// ---------------------------------------------------------------------------
template <bool OUT_BF16>
__global__ __launch_bounds__(256) void scan_pass3(
    const u16* __restrict__ gh, const float* __restrict__ carry,
    void* __restrict__ outv, float* __restrict__ nh,
    int S, int Lc, int Nc)
{
    const int tid = threadIdx.x;
    const int b  = blockIdx.x / Nc;
    const int ck = blockIdx.x % Nc;
    const u16* base = gh + (size_t)(b * S + ck * Lc) * 1024 + 4 * tid;
    const size_t cidx = (size_t)(b * Nc + ck) * 512 + 2 * tid;
    float2 st = *(const float2*)(carry + cidx);
    float h0 = st.x, h1 = st.y;
    const size_t obase = (size_t)(b * S + ck * Lc) * 512 + 2 * tid;
    #pragma unroll 4
    for (int s = 0; s < Lc; ++s) {
        ushort4 q = *(const ushort4*)(base + (size_t)s * 1024);
        h0 = fmaf(bf2f(q.x), h0, bf2f(q.y));
        h1 = fmaf(bf2f(q.z), h1, bf2f(q.w));
        if (OUT_BF16) {
            ushort2 o = make_ushort2(f2bf(h0), f2bf(h1));
            *(ushort2*)((u16*)outv + obase + (size_t)s * 512) = o;
        } else {
            *(float2*)((float*)outv + obase + (size_t)s * 512) = make_float2(h0, h1);
        }
    }
    if (ck == Nc - 1)
        *(float2*)(nh + (size_t)b * 512 + 2 * tid) = make_float2(h0, h1);
}

// ---------------------------------------------------------------------------
extern "C" void kernel_launch(void* const* d_in, const int* in_sizes, int n_in,
                              void* d_out, int out_size, void* d_ws, size_t ws_size,
                              hipStream_t stream)
{
    const float* x  = (const float*)d_in[0];
    const float* w0 = (const float*)d_in[1];
    const float* b0 = (const float*)d_in[2];
    const float* w1 = (const float*)d_in[3];
    const float* b1 = (const float*)d_in[4];
    float* out = (float*)d_out;

    const int B = 8, S = 4096, K = 512;
    const int M = B * S;             // 32768
    const int Lc = 32, Nc = S / Lc;  // 128 chunks of 32

    // workspace (bf16 elems): gh M*1024, xb M*512 (h0b aliases xb: xb is dead
    // after gemm0, which completes before pass3-L0 writes h0b), w0b/w1b.
    u16* gh  = (u16*)d_ws;
    u16* xb  = gh  + (size_t)M * 1024;
    u16* h0b = xb;                       // alias (stream-ordered safe)
    u16* w0b = xb  + (size_t)M * 512;
    u16* w1b = w0b + (size_t)1024 * 512;
    float* cA    = (float*)(w1b + (size_t)1024 * 512);
    float* cV    = cA + (size_t)B * Nc * 512;
    float* carry = cV + (size_t)B * Nc * 512;

    float* nh0 = out + (size_t)M * 512;
    float* nh1 = nh0 + (size_t)B * 512;

    dim3 blk(256);
    dim3 ggrid(8, M / 128);          // 8 channel-blocks x 256 row-blocks
    dim3 sgrid(B * Nc);              // 1024

    const int nx4 = M * K / 4;           // 4,194,304
    const int nw4 = 1024 * K / 4;        // 131,072
    cast3<<<dim3((nx4 + 2 * nw4 + 255) / 256), blk, 0, stream>>>(
        x, xb, nx4, w0, w0b, w1, w1b, nw4);

    // ---- layer 0 ----
    gemm_fused<<<ggrid, blk, 0, stream>>>(xb, w0b, b0, gh, cA, cV, K);
    scan_pass2<<<dim3(B), blk, 0, stream>>>(cA, cV, carry, Nc);
    scan_pass3<true><<<sgrid, blk, 0, stream>>>(gh, carry, h0b, nh0, S, Lc, Nc);

    // ---- layer 1 ----
    gemm_fused<<<ggrid, blk, 0, stream>>>(h0b, w1b, b1, gh, cA, cV, K);
    scan_pass2<<<dim3(B), blk, 0, stream>>>(cA, cV, carry, Nc);
    scan_pass3<false><<<sgrid, blk, 0, stream>>>(gh, carry, out, nh1, S, Lc, Nc);
}